// Round 1
// baseline (14474.197 us; speedup 1.0000x reference)
//
#include <hip/hip_runtime.h>
#include <hip/hip_bf16.h>

// Persistent-weights LSTM for MI355X.
//   B=32, T=1024, D_IN=512, H=512.
// 64 workgroups x 256 threads, all co-resident (grid << 256 CUs, 1 wg/CU).
// Each wg owns 8 h-columns (x4 gates = 32 gate cols); its [1024 x 32] f16
// weight slice ([W;U] stacked along K) lives in VGPRs for the whole kernel.
// Per time step:
//   - h-half MFMA (critical path): A-fragments read directly from the global
//     f16 h broadcast buffer (L2-hot), B-fragments from registers.
//   - gate tile -> LDS -> elementwise (c in a per-thread register) -> write
//     out (fp32) + h_next (f16) to the other broadcast buffer.
//   - stage x_{t+1} into LDS and pre-accumulate the x-half MFMAs BEFORE the
//     grid barrier (off the critical path).
//   - one device-scope barrier per step (monotonic counter in d_ws).

#define T_STEPS 1024
#define BATCH   32
#define DIN     512
#define H       512
#define NWG     64
#define HC      8          // h-columns owned per workgroup
#define XSTRIDE 536        // padded f16 row stride of LDS x tile (bank-even)
#define GSTRIDE 34         // padded f32 row stride of LDS gate tile

typedef _Float16 half8  __attribute__((ext_vector_type(8)));
typedef _Float16 half4v __attribute__((ext_vector_type(4)));
typedef float    f32x4  __attribute__((ext_vector_type(4)));

__device__ __forceinline__ float sigmoidf_(float x) {
    return 1.0f / (1.0f + __expf(-x));
}
__device__ __forceinline__ float tanhf_(float x) {
    // 1 - 2/(1+e^{2x}); saturates correctly to +-1 for large |x|
    return 1.0f - 2.0f / (1.0f + __expf(2.0f * x));
}

__global__ __launch_bounds__(256, 1) void lstm_persistent(
    const float* __restrict__ x,
    const float* __restrict__ init_states,
    const float* __restrict__ Wi, const float* __restrict__ Ui, const float* __restrict__ bi,
    const float* __restrict__ Wf, const float* __restrict__ Uf, const float* __restrict__ bf,
    const float* __restrict__ Wc, const float* __restrict__ Uc, const float* __restrict__ bc,
    const float* __restrict__ Wo, const float* __restrict__ Uo, const float* __restrict__ bo,
    float* __restrict__ out,
    unsigned* bar,
    _Float16* hbuf)            // two buffers of BATCH*H f16 each
{
    __shared__ _Float16 xbuf[BATCH * XSTRIDE];   // ~33.5 KB
    __shared__ float    gbuf[BATCH * GSTRIDE];   // ~4.3 KB

    const int tid  = threadIdx.x;
    const int wg   = blockIdx.x;
    const int lane = tid & 63;
    const int wave = tid >> 6;          // 4 waves
    const int mt   = wave & 1;          // M tile (batches 0-15 / 16-31)
    const int nt   = wave >> 1;         // N tile (gate cols 0-15 / 16-31 local)
    const int row  = mt * 16 + (lane & 15);
    const int kq   = lane >> 4;         // k-quad 0..3

    // ---- one-time: weight B-fragments into VGPRs --------------------------
    // wg-local gate col n_local: [0..7]=i, [8..15]=f, [16..23]=g, [24..31]=o
    const int n_local = lane & 15;
    const int gi   = nt * 2 + (n_local >> 3);
    const int wcol = wg * HC + (n_local & 7);
    const float* Wmat = (gi == 0) ? Wi : (gi == 1) ? Wf : (gi == 2) ? Wc : Wo;
    const float* Umat = (gi == 0) ? Ui : (gi == 1) ? Uf : (gi == 2) ? Uc : Uo;

    half8 bfrag[32];                    // 128 VGPRs/lane, persistent
    #pragma unroll
    for (int kk = 0; kk < 16; ++kk) {
        #pragma unroll
        for (int jj = 0; jj < 8; ++jj) {
            int k = kk * 32 + kq * 8 + jj;           // 0..511
            bfrag[kk][jj]      = (_Float16)Wmat[k * H + wcol];
            bfrag[16 + kk][jj] = (_Float16)Umat[k * H + wcol];
        }
    }

    // ---- elementwise identity: thread (eb, ej) owns c[eb][wg*8+ej] --------
    const int eb   = tid >> 3;          // batch 0..31
    const int ej   = tid & 7;           // local h-col 0..7
    const int ecol = wg * HC + ej;

    float c_state = init_states[BATCH * H + eb * H + ecol];
    // publish h0 (f16) into broadcast buffer 0 (owner writes its slice)
    hbuf[eb * H + ecol] = (_Float16)init_states[eb * H + ecol];

    const float bi_v = bi[ecol], bf_v = bf[ecol], bc_v = bc[ecol], bo_v = bo[ecol];

    // ---- stage x_0 into LDS (f16) -----------------------------------------
    {
        const int sb = tid >> 3;
        const int so = (tid & 7) * 4;
        const float* xr = x + ((size_t)sb * T_STEPS + 0) * DIN;
        #pragma unroll
        for (int q = 0; q < 16; ++q) {
            int colq = so + q * 32;
            float4 v = *(const float4*)(xr + colq);
            half4v hv = { (_Float16)v.x, (_Float16)v.y, (_Float16)v.z, (_Float16)v.w };
            *(half4v*)&xbuf[sb * XSTRIDE + colq] = hv;
        }
    }
    __syncthreads();

    // ---- x-half pre-accumulation for step 0 -------------------------------
    f32x4 acc_x = {0.f, 0.f, 0.f, 0.f};
    {
        const _Float16* xr = &xbuf[row * XSTRIDE + kq * 8];
        #pragma unroll
        for (int kk = 0; kk < 16; ++kk) {
            half8 a = *(const half8*)(xr + kk * 32);
            acc_x = __builtin_amdgcn_mfma_f32_16x16x32_f16(a, bfrag[kk], acc_x, 0, 0, 0);
        }
    }

    // ---- initial grid barrier (h0 published) ------------------------------
    __threadfence();
    __syncthreads();
    if (tid == 0) {
        __hip_atomic_fetch_add(bar, 1u, __ATOMIC_ACQ_REL, __HIP_MEMORY_SCOPE_AGENT);
        unsigned spins = 0;
        while (__hip_atomic_load(bar, __ATOMIC_ACQUIRE, __HIP_MEMORY_SCOPE_AGENT) < NWG) {
            __builtin_amdgcn_s_sleep(1);
            if (++spins > 200000u) break;   // safety valve (normal: <100 polls)
        }
    }
    __syncthreads();
    __threadfence();

    // ---- main recurrence --------------------------------------------------
    for (int t = 0; t < T_STEPS; ++t) {
        // h-half matmul: A fragments straight from global broadcast buffer
        {
            const _Float16* hb =
                hbuf + (size_t)(t & 1) * (BATCH * H) + row * H + kq * 8;
            f32x4 acc  = acc_x;
            f32x4 acc2 = {0.f, 0.f, 0.f, 0.f};
            #pragma unroll
            for (int kk = 0; kk < 16; kk += 2) {
                half8 a0 = *(const half8*)(hb + kk * 32);
                half8 a1 = *(const half8*)(hb + (kk + 1) * 32);
                acc  = __builtin_amdgcn_mfma_f32_16x16x32_f16(a0, bfrag[16 + kk],     acc,  0, 0, 0);
                acc2 = __builtin_amdgcn_mfma_f32_16x16x32_f16(a1, bfrag[16 + kk + 1], acc2, 0, 0, 0);
            }
            #pragma unroll
            for (int r = 0; r < 4; ++r) {
                // C/D layout: col = lane&15, row = (lane>>4)*4 + r
                gbuf[(mt * 16 + kq * 4 + r) * GSTRIDE + nt * 16 + n_local] =
                    acc[r] + acc2[r];
            }
        }
        __syncthreads();

        // elementwise gates + state update + outputs
        {
            float pi = gbuf[eb * GSTRIDE + ej]      + bi_v;
            float pf = gbuf[eb * GSTRIDE + 8 + ej]  + bf_v;
            float pg = gbuf[eb * GSTRIDE + 16 + ej] + bc_v;
            float po = gbuf[eb * GSTRIDE + 24 + ej] + bo_v;
            float ig = sigmoidf_(pi);
            float fg = sigmoidf_(pf);
            float gg = tanhf_(pg);
            float og = sigmoidf_(po);
            c_state  = fg * c_state + ig * gg;
            float h  = og * tanhf_(c_state);
            out[((size_t)eb * T_STEPS + t) * H + ecol] = h;
            hbuf[(size_t)((t + 1) & 1) * (BATCH * H) + eb * H + ecol] = (_Float16)h;
        }

        if (t + 1 < T_STEPS) {
            // stage x_{t+1} (xbuf reads for step t finished last iteration,
            // ordered by the barrier's __syncthreads)
            {
                const int sb = tid >> 3;
                const int so = (tid & 7) * 4;
                const float* xr = x + ((size_t)sb * T_STEPS + (t + 1)) * DIN;
                #pragma unroll
                for (int q = 0; q < 16; ++q) {
                    int colq = so + q * 32;
                    float4 v = *(const float4*)(xr + colq);
                    half4v hv = { (_Float16)v.x, (_Float16)v.y,
                                  (_Float16)v.z, (_Float16)v.w };
                    *(half4v*)&xbuf[sb * XSTRIDE + colq] = hv;
                }
            }
            __syncthreads();   // staging visible; also fences gbuf reuse

            // x-half pre-accumulation for step t+1 (off critical path)
            {
                f32x4 ax  = {0.f, 0.f, 0.f, 0.f};
                f32x4 ax2 = {0.f, 0.f, 0.f, 0.f};
                const _Float16* xr2 = &xbuf[row * XSTRIDE + kq * 8];
                #pragma unroll
                for (int kk = 0; kk < 16; kk += 2) {
                    half8 a0 = *(const half8*)(xr2 + kk * 32);
                    half8 a1 = *(const half8*)(xr2 + (kk + 1) * 32);
                    ax  = __builtin_amdgcn_mfma_f32_16x16x32_f16(a0, bfrag[kk],     ax,  0, 0, 0);
                    ax2 = __builtin_amdgcn_mfma_f32_16x16x32_f16(a1, bfrag[kk + 1], ax2, 0, 0, 0);
                }
                #pragma unroll
                for (int r = 0; r < 4; ++r) acc_x[r] = ax[r] + ax2[r];
            }

            // grid barrier: h_{t+1} published, everyone advances together
            __threadfence();
            __syncthreads();
            if (tid == 0) {
                __hip_atomic_fetch_add(bar, 1u, __ATOMIC_ACQ_REL, __HIP_MEMORY_SCOPE_AGENT);
                const unsigned target = (unsigned)(t + 2) * NWG;
                unsigned spins = 0;
                while (__hip_atomic_load(bar, __ATOMIC_ACQUIRE, __HIP_MEMORY_SCOPE_AGENT) < target) {
                    __builtin_amdgcn_s_sleep(1);
                    if (++spins > 200000u) break;
                }
            }
            __syncthreads();
            __threadfence();
        }
    }
}

extern "C" void kernel_launch(void* const* d_in, const int* in_sizes, int n_in,
                              void* d_out, int out_size, void* d_ws, size_t ws_size,
                              hipStream_t stream) {
    const float* x           = (const float*)d_in[0];
    const float* init_states = (const float*)d_in[1];
    const float* Wi = (const float*)d_in[2];
    const float* Ui = (const float*)d_in[3];
    const float* bi = (const float*)d_in[4];
    const float* Wf = (const float*)d_in[5];
    const float* Uf = (const float*)d_in[6];
    const float* bf = (const float*)d_in[7];
    const float* Wc = (const float*)d_in[8];
    const float* Uc = (const float*)d_in[9];
    const float* bc = (const float*)d_in[10];
    const float* Wo = (const float*)d_in[11];
    const float* Uo = (const float*)d_in[12];
    const float* bo = (const float*)d_in[13];
    float* out = (float*)d_out;

    // ws layout: [0..255] barrier counter (zeroed every launch; harness
    // poisons ws with 0xAA), [256 ..] two f16 h broadcast buffers (32 KB each,
    // written before first read in-kernel).
    unsigned char* ws = (unsigned char*)d_ws;
    unsigned* bar   = (unsigned*)ws;
    _Float16* hbuf  = (_Float16*)(ws + 256);

    hipMemsetAsync(bar, 0, 256, stream);
    lstm_persistent<<<dim3(NWG), dim3(256), 0, stream>>>(
        x, init_states, Wi, Ui, bi, Wf, Uf, bf, Wc, Uc, bc, Wo, Uo, bo,
        out, bar, hbuf);
}

// Round 2
// 6787.852 us; speedup vs baseline: 2.1324x; 2.1324x over previous
//
#include <hip/hip_runtime.h>
#include <hip/hip_bf16.h>

// Persistent-weights LSTM for MI355X.  B=32, T=1024, D_IN=512, H=512.
// 64 WGs x 256 threads, all co-resident. Each WG owns 8 h-cols x 4 gates;
// its [1024 x 32] f16 weight slice lives in VGPRs (128/lane) all run.
//
// Round-2 change: fence-free grid barrier. Cross-WG data (h broadcast,
// counter) moves via per-instruction agent-scope relaxed atomics (sc-bit
// write-through / L2-bypass loads). No __threadfence, no acquire-per-poll:
// previously every poll emitted buffer_inv and every step emitted
// buffer_wbl2, flushing the XCD L2 ~continuously (the 14 us/step).
// __syncthreads drains vmcnt(0) per wave, so h stores are at the coherence
// point before tid0's relaxed fetch_add; readers poll relaxed and pull h
// with agent-scope 8B loads (L2-bypassed, LLC-hot).

#define T_STEPS 1024
#define BATCH   32
#define DIN     512
#define H       512
#define NWG     64
#define HC      8
#define XSTRIDE 520        // f16 elems; 1040B row = bank offset 4 -> 2-way max (free)
#define GSTRIDE 34         // padded f32 row stride of LDS gate tile

typedef _Float16 half8  __attribute__((ext_vector_type(8)));
typedef _Float16 half4v __attribute__((ext_vector_type(4)));
typedef float    f32x4  __attribute__((ext_vector_type(4)));

#define AT_LD_U64(p) __hip_atomic_load((const unsigned long long*)(p), __ATOMIC_RELAXED, __HIP_MEMORY_SCOPE_AGENT)
#define AT_LD_U32(p) __hip_atomic_load((const unsigned*)(p),           __ATOMIC_RELAXED, __HIP_MEMORY_SCOPE_AGENT)
#define AT_ST_U32(p,v) __hip_atomic_store((unsigned*)(p), (v),         __ATOMIC_RELAXED, __HIP_MEMORY_SCOPE_AGENT)

__device__ __forceinline__ float sigmoidf_(float x) {
    return 1.0f / (1.0f + __expf(-x));
}
__device__ __forceinline__ float tanhf_(float x) {
    return 1.0f - 2.0f / (1.0f + __expf(2.0f * x));
}

__global__ __launch_bounds__(256, 1) void lstm_persistent(
    const float* __restrict__ x,
    const float* __restrict__ init_states,
    const float* __restrict__ Wi, const float* __restrict__ Ui, const float* __restrict__ bi,
    const float* __restrict__ Wf, const float* __restrict__ Uf, const float* __restrict__ bf,
    const float* __restrict__ Wc, const float* __restrict__ Uc, const float* __restrict__ bc,
    const float* __restrict__ Wo, const float* __restrict__ Uo, const float* __restrict__ bo,
    float* __restrict__ out,
    unsigned* bar,
    _Float16* hbuf)            // two buffers of BATCH*H f16 each
{
    __shared__ _Float16 xbuf[2 * BATCH * XSTRIDE];   // ~65 KB, double-buffered
    __shared__ float    gbuf[BATCH * GSTRIDE];       // ~4.3 KB

    const int tid  = threadIdx.x;
    const int wg   = blockIdx.x;
    const int lane = tid & 63;
    const int wave = tid >> 6;
    const int mt   = wave & 1;
    const int nt   = wave >> 1;
    const int row  = mt * 16 + (lane & 15);
    const int kq   = lane >> 4;

    // ---- one-time: weight B-fragments into VGPRs --------------------------
    const int n_local = lane & 15;
    const int gi   = nt * 2 + (n_local >> 3);
    const int wcol = wg * HC + (n_local & 7);
    const float* Wmat = (gi == 0) ? Wi : (gi == 1) ? Wf : (gi == 2) ? Wc : Wo;
    const float* Umat = (gi == 0) ? Ui : (gi == 1) ? Uf : (gi == 2) ? Uc : Uo;

    half8 bfrag[32];
    #pragma unroll
    for (int kk = 0; kk < 16; ++kk) {
        #pragma unroll
        for (int jj = 0; jj < 8; ++jj) {
            int k = kk * 32 + kq * 8 + jj;
            bfrag[kk][jj]      = (_Float16)Wmat[k * H + wcol];
            bfrag[16 + kk][jj] = (_Float16)Umat[k * H + wcol];
        }
    }

    // ---- elementwise identity ---------------------------------------------
    const int eb   = tid >> 3;
    const int ej   = tid & 7;
    const int ecol = wg * HC + ej;

    float c_state = init_states[BATCH * H + eb * H + ecol];
    const float bi_v = bi[ecol], bf_v = bf[ecol], bc_v = bc[ecol], bo_v = bo[ecol];

    // publish h0 (f16 pairs, agent-scope write-through)
    {
        _Float16 h0 = (_Float16)init_states[eb * H + ecol];
        unsigned hu = (unsigned)__builtin_bit_cast(unsigned short, h0);
        unsigned oth = __shfl_down(hu, 1);
        if ((tid & 1) == 0)
            AT_ST_U32(&hbuf[eb * H + ecol], hu | (oth << 16));
    }

    // ---- staging / x-MFMA helpers -----------------------------------------
    auto stage = [&](int t, int buf) {
        const int sb = tid >> 3;
        const int so = (tid & 7) * 4;
        const float* xr = x + ((size_t)sb * T_STEPS + t) * DIN;
        _Float16* xb = &xbuf[buf * (BATCH * XSTRIDE)];
        #pragma unroll
        for (int q = 0; q < 16; ++q) {
            int colq = so + q * 32;
            float4 v = *(const float4*)(xr + colq);
            half4v hv = { (_Float16)v.x, (_Float16)v.y,
                          (_Float16)v.z, (_Float16)v.w };
            *(half4v*)&xb[sb * XSTRIDE + colq] = hv;
        }
    };
    auto xmm = [&](int buf) -> f32x4 {
        f32x4 ax  = {0.f, 0.f, 0.f, 0.f};
        f32x4 ax2 = {0.f, 0.f, 0.f, 0.f};
        const _Float16* xr2 = &xbuf[buf * (BATCH * XSTRIDE) + row * XSTRIDE + kq * 8];
        #pragma unroll
        for (int kk = 0; kk < 16; kk += 2) {
            half8 a0 = *(const half8*)(xr2 + kk * 32);
            half8 a1 = *(const half8*)(xr2 + (kk + 1) * 32);
            ax  = __builtin_amdgcn_mfma_f32_16x16x32_f16(a0, bfrag[kk],     ax,  0, 0, 0);
            ax2 = __builtin_amdgcn_mfma_f32_16x16x32_f16(a1, bfrag[kk + 1], ax2, 0, 0, 0);
        }
        #pragma unroll
        for (int r = 0; r < 4; ++r) ax[r] += ax2[r];
        return ax;
    };

    // ---- prologue: stage x0,x1; drain h0; x-MFMA(0); initial barrier ------
    stage(0, 0);
    stage(1, 1);
    __builtin_amdgcn_fence(__ATOMIC_RELEASE, "workgroup");
    __syncthreads();                 // drains h0 stores (vmcnt 0) + staging

    f32x4 acc_x = xmm(0);

    if (tid == 0)
        __hip_atomic_fetch_add(bar, 1u, __ATOMIC_RELAXED, __HIP_MEMORY_SCOPE_AGENT);
    if (tid == 0) {
        unsigned spins = 0;
        while (AT_LD_U32(bar) < NWG) {
            __builtin_amdgcn_s_sleep(1);
            if (++spins > 4000000u) break;
        }
    }
    __syncthreads();
    __builtin_amdgcn_fence(__ATOMIC_ACQUIRE, "workgroup");

    // ---- main recurrence --------------------------------------------------
    for (int t = 0; t < T_STEPS; ++t) {
        // h-half matmul: A fragments via agent-scope 8B loads (LLC-hot)
        {
            const _Float16* hb =
                hbuf + (size_t)(t & 1) * (BATCH * H) + row * H + kq * 8;
            f32x4 acc  = acc_x;
            f32x4 acc2 = {0.f, 0.f, 0.f, 0.f};
            #pragma unroll
            for (int kk = 0; kk < 16; kk += 2) {
                union { unsigned long long u[2]; half8 h; } a0, a1;
                a0.u[0] = AT_LD_U64(hb + kk * 32);
                a0.u[1] = AT_LD_U64(hb + kk * 32 + 4);
                a1.u[0] = AT_LD_U64(hb + (kk + 1) * 32);
                a1.u[1] = AT_LD_U64(hb + (kk + 1) * 32 + 4);
                acc  = __builtin_amdgcn_mfma_f32_16x16x32_f16(a0.h, bfrag[16 + kk],     acc,  0, 0, 0);
                acc2 = __builtin_amdgcn_mfma_f32_16x16x32_f16(a1.h, bfrag[16 + kk + 1], acc2, 0, 0, 0);
            }
            #pragma unroll
            for (int r = 0; r < 4; ++r) {
                // C/D layout: col = lane&15, row = (lane>>4)*4 + r
                gbuf[(mt * 16 + kq * 4 + r) * GSTRIDE + nt * 16 + n_local] =
                    acc[r] + acc2[r];
            }
        }
        __syncthreads();

        // elementwise gates + state update + publish h_{t+1}
        {
            float pi = gbuf[eb * GSTRIDE + ej]      + bi_v;
            float pf = gbuf[eb * GSTRIDE + 8 + ej]  + bf_v;
            float pg = gbuf[eb * GSTRIDE + 16 + ej] + bc_v;
            float po = gbuf[eb * GSTRIDE + 24 + ej] + bo_v;
            float ig = sigmoidf_(pi);
            float fg = sigmoidf_(pf);
            float gg = tanhf_(pg);
            float og = sigmoidf_(po);
            c_state  = fg * c_state + ig * gg;
            float h  = og * tanhf_(c_state);
            out[((size_t)eb * T_STEPS + t) * H + ecol] = h;

            _Float16 hh = (_Float16)h;
            unsigned hu = (unsigned)__builtin_bit_cast(unsigned short, hh);
            unsigned oth = __shfl_down(hu, 1);
            if ((tid & 1) == 0)
                AT_ST_U32(&hbuf[(size_t)((t + 1) & 1) * (BATCH * H) + eb * H + ecol],
                          hu | (oth << 16));
        }
        __builtin_amdgcn_fence(__ATOMIC_RELEASE, "workgroup");
        __syncthreads();             // per-wave vmcnt(0): h stores at LLC

        if (t + 1 < T_STEPS) {
            // arrive FIRST (minimizes other WGs' wait), then do local work
            if (tid == 0)
                __hip_atomic_fetch_add(bar, 1u, __ATOMIC_RELAXED, __HIP_MEMORY_SCOPE_AGENT);

            // x-half pre-accumulation for t+1 (staged last iteration)
            acc_x = xmm((t + 1) & 1);
            // stage x_{t+2} into the buffer consumed two steps from now
            if (t + 2 < T_STEPS) stage(t + 2, t & 1);

            if (tid == 0) {
                const unsigned target = (unsigned)(t + 2) * NWG;
                unsigned spins = 0;
                while (AT_LD_U32(bar) < target) {
                    __builtin_amdgcn_s_sleep(1);
                    if (++spins > 4000000u) break;
                }
            }
            __syncthreads();
            __builtin_amdgcn_fence(__ATOMIC_ACQUIRE, "workgroup");
        }
    }
}

extern "C" void kernel_launch(void* const* d_in, const int* in_sizes, int n_in,
                              void* d_out, int out_size, void* d_ws, size_t ws_size,
                              hipStream_t stream) {
    const float* x           = (const float*)d_in[0];
    const float* init_states = (const float*)d_in[1];
    const float* Wi = (const float*)d_in[2];
    const float* Ui = (const float*)d_in[3];
    const float* bi = (const float*)d_in[4];
    const float* Wf = (const float*)d_in[5];
    const float* Uf = (const float*)d_in[6];
    const float* bf = (const float*)d_in[7];
    const float* Wc = (const float*)d_in[8];
    const float* Uc = (const float*)d_in[9];
    const float* bc = (const float*)d_in[10];
    const float* Wo = (const float*)d_in[11];
    const float* Uo = (const float*)d_in[12];
    const float* bo = (const float*)d_in[13];
    float* out = (float*)d_out;

    unsigned char* ws = (unsigned char*)d_ws;
    unsigned* bar   = (unsigned*)ws;
    _Float16* hbuf  = (_Float16*)(ws + 256);

    hipMemsetAsync(bar, 0, 256, stream);
    lstm_persistent<<<dim3(NWG), dim3(256), 0, stream>>>(
        x, init_states, Wi, Ui, bi, Wf, Uf, bf, Wc, Uc, bc, Wo, Uo, bo,
        out, bar, hbuf);
}

// Round 3
// 6739.324 us; speedup vs baseline: 2.1477x; 1.0072x over previous
//
#include <hip/hip_runtime.h>
#include <hip/hip_bf16.h>

// Persistent-weights LSTM for MI355X.  B=32, T=1024, D_IN=512, H=512.
// 64 WGs x 256 threads, all co-resident. Each WG owns 8 h-cols x 4 gates;
// its [1024 x 32] f16 weight slice lives in VGPRs (128/lane) all run.
//
// R3: contention-free grid barrier. The R2 central atomic counter meant 64
// serialized RMWs on one line per step (~3-4 us). Now: 64 per-WG epoch
// flags (4 cache lines); producers relaxed-STORE flags[wg]=epoch after the
// h write-through drain (fire-and-forget, pipelined), and ALL waves of
// every WG poll all 64 flags directly (lane i <-> flag i) then go straight
// into their h loads — no tid0 relay, no post-poll __syncthreads.
// Cross-WG data still moves via agent-scope relaxed atomics (write-through
// to the coherence point / L2-bypass loads); workgroup release fence +
// __syncthreads provides the per-wave vmcnt(0) drain before flag publish.

#define T_STEPS 1024
#define BATCH   32
#define DIN     512
#define H       512
#define NWG     64
#define HC      8
#define XSTRIDE 520        // f16 elems; 1040B row = bank offset 4 -> 2-way max (free)
#define GSTRIDE 34         // padded f32 row stride of LDS gate tile

typedef _Float16 half8  __attribute__((ext_vector_type(8)));
typedef _Float16 half4v __attribute__((ext_vector_type(4)));
typedef float    f32x4  __attribute__((ext_vector_type(4)));

#define AT_LD_U64(p) __hip_atomic_load((const unsigned long long*)(p), __ATOMIC_RELAXED, __HIP_MEMORY_SCOPE_AGENT)
#define AT_LD_U32(p) __hip_atomic_load((const unsigned*)(p),           __ATOMIC_RELAXED, __HIP_MEMORY_SCOPE_AGENT)
#define AT_ST_U32(p,v) __hip_atomic_store((unsigned*)(p), (v),         __ATOMIC_RELAXED, __HIP_MEMORY_SCOPE_AGENT)

__device__ __forceinline__ float sigmoidf_(float x) {
    return 1.0f / (1.0f + __expf(-x));
}
__device__ __forceinline__ float tanhf_(float x) {
    return 1.0f - 2.0f / (1.0f + __expf(2.0f * x));
}

__global__ __launch_bounds__(256, 1) void lstm_persistent(
    const float* __restrict__ x,
    const float* __restrict__ init_states,
    const float* __restrict__ Wi, const float* __restrict__ Ui, const float* __restrict__ bi,
    const float* __restrict__ Wf, const float* __restrict__ Uf, const float* __restrict__ bf,
    const float* __restrict__ Wc, const float* __restrict__ Uc, const float* __restrict__ bc,
    const float* __restrict__ Wo, const float* __restrict__ Uo, const float* __restrict__ bo,
    float* __restrict__ out,
    unsigned* flags,           // 64 per-WG epoch flags
    _Float16* hbuf)            // two buffers of BATCH*H f16 each
{
    __shared__ _Float16 xbuf[2 * BATCH * XSTRIDE];   // ~65 KB, double-buffered
    __shared__ float    gbuf[BATCH * GSTRIDE];       // ~4.3 KB

    const int tid  = threadIdx.x;
    const int wg   = blockIdx.x;
    const int lane = tid & 63;
    const int wave = tid >> 6;
    const int mt   = wave & 1;
    const int nt   = wave >> 1;
    const int row  = mt * 16 + (lane & 15);
    const int kq   = lane >> 4;

    // ---- one-time: weight B-fragments into VGPRs --------------------------
    const int n_local = lane & 15;
    const int gi   = nt * 2 + (n_local >> 3);
    const int wcol = wg * HC + (n_local & 7);
    const float* Wmat = (gi == 0) ? Wi : (gi == 1) ? Wf : (gi == 2) ? Wc : Wo;
    const float* Umat = (gi == 0) ? Ui : (gi == 1) ? Uf : (gi == 2) ? Uc : Uo;

    half8 bfrag[32];
    #pragma unroll
    for (int kk = 0; kk < 16; ++kk) {
        #pragma unroll
        for (int jj = 0; jj < 8; ++jj) {
            int k = kk * 32 + kq * 8 + jj;
            bfrag[kk][jj]      = (_Float16)Wmat[k * H + wcol];
            bfrag[16 + kk][jj] = (_Float16)Umat[k * H + wcol];
        }
    }

    // ---- elementwise identity ---------------------------------------------
    const int eb   = tid >> 3;
    const int ej   = tid & 7;
    const int ecol = wg * HC + ej;

    float c_state = init_states[BATCH * H + eb * H + ecol];
    const float bi_v = bi[ecol], bf_v = bf[ecol], bc_v = bc[ecol], bo_v = bo[ecol];

    // publish h0 (f16 pairs, agent-scope write-through)
    {
        _Float16 h0 = (_Float16)init_states[eb * H + ecol];
        unsigned hu = (unsigned)__builtin_bit_cast(unsigned short, h0);
        unsigned oth = __shfl_down(hu, 1);
        if ((tid & 1) == 0)
            AT_ST_U32(&hbuf[eb * H + ecol], hu | (oth << 16));
    }

    // ---- staging / x-MFMA helpers -----------------------------------------
    auto stage = [&](int t, int buf) {
        const int sb = tid >> 3;
        const int so = (tid & 7) * 4;
        const float* xr = x + ((size_t)sb * T_STEPS + t) * DIN;
        _Float16* xb = &xbuf[buf * (BATCH * XSTRIDE)];
        #pragma unroll
        for (int q = 0; q < 16; ++q) {
            int colq = so + q * 32;
            float4 v = *(const float4*)(xr + colq);
            half4v hv = { (_Float16)v.x, (_Float16)v.y,
                          (_Float16)v.z, (_Float16)v.w };
            *(half4v*)&xb[sb * XSTRIDE + colq] = hv;
        }
    };
    auto xmm = [&](int buf) -> f32x4 {
        f32x4 ax  = {0.f, 0.f, 0.f, 0.f};
        f32x4 ax2 = {0.f, 0.f, 0.f, 0.f};
        const _Float16* xr2 = &xbuf[buf * (BATCH * XSTRIDE) + row * XSTRIDE + kq * 8];
        #pragma unroll
        for (int kk = 0; kk < 16; kk += 2) {
            half8 a0 = *(const half8*)(xr2 + kk * 32);
            half8 a1 = *(const half8*)(xr2 + (kk + 1) * 32);
            ax  = __builtin_amdgcn_mfma_f32_16x16x32_f16(a0, bfrag[kk],     ax,  0, 0, 0);
            ax2 = __builtin_amdgcn_mfma_f32_16x16x32_f16(a1, bfrag[kk + 1], ax2, 0, 0, 0);
        }
        #pragma unroll
        for (int r = 0; r < 4; ++r) ax[r] += ax2[r];
        return ax;
    };

    // ---- prologue: stage x0,x1; drain h0; publish flag=1; x-MFMA(0) -------
    stage(0, 0);
    stage(1, 1);
    __builtin_amdgcn_fence(__ATOMIC_RELEASE, "workgroup");
    __syncthreads();                 // per-wave vmcnt(0): h0 at coherence pt
    if (tid == 0) AT_ST_U32(&flags[wg], 1u);

    f32x4 acc_x = xmm(0);

    // ---- main recurrence --------------------------------------------------
    for (int t = 0; t < T_STEPS; ++t) {
        // all-wave flag poll: lane i watches WG i's epoch (4 cache lines)
        {
            const unsigned target = (unsigned)(t + 1);
            unsigned spins = 0;
            while (AT_LD_U32(&flags[lane]) < target) {
                if (++spins > 2000000u) break;   // deadlock safety valve
            }
        }
        __builtin_amdgcn_fence(__ATOMIC_ACQUIRE, "workgroup");

        // h-half matmul: A fragments via agent-scope 8B loads (LLC-hot)
        {
            const _Float16* hb =
                hbuf + (size_t)(t & 1) * (BATCH * H) + row * H + kq * 8;
            f32x4 acc  = acc_x;
            f32x4 acc2 = {0.f, 0.f, 0.f, 0.f};
            #pragma unroll
            for (int kk = 0; kk < 16; kk += 2) {
                union { unsigned long long u[2]; half8 h; } a0, a1;
                a0.u[0] = AT_LD_U64(hb + kk * 32);
                a0.u[1] = AT_LD_U64(hb + kk * 32 + 4);
                a1.u[0] = AT_LD_U64(hb + (kk + 1) * 32);
                a1.u[1] = AT_LD_U64(hb + (kk + 1) * 32 + 4);
                acc  = __builtin_amdgcn_mfma_f32_16x16x32_f16(a0.h, bfrag[16 + kk],     acc,  0, 0, 0);
                acc2 = __builtin_amdgcn_mfma_f32_16x16x32_f16(a1.h, bfrag[16 + kk + 1], acc2, 0, 0, 0);
            }
            #pragma unroll
            for (int r = 0; r < 4; ++r) {
                // C/D layout: col = lane&15, row = (lane>>4)*4 + r
                gbuf[(mt * 16 + kq * 4 + r) * GSTRIDE + nt * 16 + n_local] =
                    acc[r] + acc2[r];
            }
        }
        __syncthreads();

        // elementwise gates + state update + publish h_{t+1}
        float h_val;
        {
            float pi = gbuf[eb * GSTRIDE + ej]      + bi_v;
            float pf = gbuf[eb * GSTRIDE + 8 + ej]  + bf_v;
            float pg = gbuf[eb * GSTRIDE + 16 + ej] + bc_v;
            float po = gbuf[eb * GSTRIDE + 24 + ej] + bo_v;
            float ig = sigmoidf_(pi);
            float fg = sigmoidf_(pf);
            float gg = tanhf_(pg);
            float og = sigmoidf_(po);
            c_state  = fg * c_state + ig * gg;
            h_val    = og * tanhf_(c_state);

            _Float16 hh = (_Float16)h_val;
            unsigned hu = (unsigned)__builtin_bit_cast(unsigned short, hh);
            unsigned oth = __shfl_down(hu, 1);
            if ((tid & 1) == 0)
                AT_ST_U32(&hbuf[(size_t)((t + 1) & 1) * (BATCH * H) + eb * H + ecol],
                          hu | (oth << 16));
        }
        __builtin_amdgcn_fence(__ATOMIC_RELEASE, "workgroup");
        __syncthreads();             // per-wave vmcnt(0): h stores at LLC

        // arrival: fire-and-forget epoch store (no RMW, no contention)
        if (tid == 0) AT_ST_U32(&flags[wg], (unsigned)(t + 2));

        // ---- off-critical-path tail ----
        out[((size_t)eb * T_STEPS + t) * H + ecol] = h_val;
        if (t + 1 < T_STEPS) {
            acc_x = xmm((t + 1) & 1);                 // staged last iteration
            if (t + 2 < T_STEPS) stage(t + 2, t & 1); // buffer read 2 steps ago
        }
    }
}

extern "C" void kernel_launch(void* const* d_in, const int* in_sizes, int n_in,
                              void* d_out, int out_size, void* d_ws, size_t ws_size,
                              hipStream_t stream) {
    const float* x           = (const float*)d_in[0];
    const float* init_states = (const float*)d_in[1];
    const float* Wi = (const float*)d_in[2];
    const float* Ui = (const float*)d_in[3];
    const float* bi = (const float*)d_in[4];
    const float* Wf = (const float*)d_in[5];
    const float* Uf = (const float*)d_in[6];
    const float* bf = (const float*)d_in[7];
    const float* Wc = (const float*)d_in[8];
    const float* Uc = (const float*)d_in[9];
    const float* bc = (const float*)d_in[10];
    const float* Wo = (const float*)d_in[11];
    const float* Uo = (const float*)d_in[12];
    const float* bo = (const float*)d_in[13];
    float* out = (float*)d_out;

    // ws layout: [0..511] 64 u32 epoch flags (+pad), zeroed every launch
    // (harness poisons ws with 0xAA); [1024..] two f16 h buffers (32 KB each,
    // written before first read in-kernel, guarded by flags).
    unsigned char* ws = (unsigned char*)d_ws;
    unsigned* flags = (unsigned*)ws;
    _Float16* hbuf  = (_Float16*)(ws + 1024);

    hipMemsetAsync(flags, 0, 512, stream);
    lstm_persistent<<<dim3(NWG), dim3(256), 0, stream>>>(
        x, init_states, Wi, Ui, bi, Wf, Uf, bf, Wc, Uc, bc, Wo, Uo, bo,
        out, flags, hbuf);
}

// Round 4
// 5245.187 us; speedup vs baseline: 2.7595x; 1.2849x over previous
//
#include <hip/hip_runtime.h>
#include <hip/hip_bf16.h>

// Persistent-weights LSTM for MI355X.  B=32, T=1024, D_IN=512, H=512.
// 64 WGs x 256 threads, all co-resident. Each WG owns 8 h-cols x 4 gates;
// its [1024 x 32] f16 weight slice lives in VGPRs (128/lane) all run.
//
// R4: drain-free h exchange. h moves as 8B records {epoch(hi32) | 2xf16 (lo32)}
// via relaxed agent-scope 8B atomics. A record is self-validating (8B store
// atomicity), so: NO producer vmcnt drain, NO flag, NO release fence — the
// publish is ONE LLC hop. Consumers poll the data itself: load their 64
// records (fully coalesced: layout is A-fragment consumption order,
// u64 idx = kk*512 + s*128 + row*4 + kq), retry until all epochs == t+1.
// Double-buffered by parity (a WG can't run 2 steps ahead: overwriting
// epoch E+2 requires passing poll(E+1), which requires every WG published
// E+1, which happens after they read E). Exact-match epochs make the 0xAA
// ws poison harmless. gbuf is LDS-double-buffered -> 1 __syncthreads/step.

#define T_STEPS 1024
#define BATCH   32
#define DIN     512
#define H       512
#define NWG     64
#define HC      8
#define XSTRIDE 520        // f16 elems; 1040B row = bank offset 4 -> 2-way max (free)
#define GSTRIDE 34         // padded f32 row stride of LDS gate tile
#define RECS_PER_PARITY 8192   // 16 kk * 512

typedef _Float16 half8  __attribute__((ext_vector_type(8)));
typedef _Float16 half4v __attribute__((ext_vector_type(4)));
typedef float    f32x4  __attribute__((ext_vector_type(4)));
typedef unsigned long long u64;
typedef unsigned int       u32;

#define AT_LD_U64(p)   __hip_atomic_load((const u64*)(p), __ATOMIC_RELAXED, __HIP_MEMORY_SCOPE_AGENT)
#define AT_ST_U64(p,v) __hip_atomic_store((u64*)(p), (v), __ATOMIC_RELAXED, __HIP_MEMORY_SCOPE_AGENT)

__device__ __forceinline__ float sigmoidf_(float x) {
    return 1.0f / (1.0f + __expf(-x));
}
__device__ __forceinline__ float tanhf_(float x) {
    return 1.0f - 2.0f / (1.0f + __expf(2.0f * x));
}

__global__ __launch_bounds__(256, 1) void lstm_persistent(
    const float* __restrict__ x,
    const float* __restrict__ init_states,
    const float* __restrict__ Wi, const float* __restrict__ Ui, const float* __restrict__ bi,
    const float* __restrict__ Wf, const float* __restrict__ Uf, const float* __restrict__ bf,
    const float* __restrict__ Wc, const float* __restrict__ Uc, const float* __restrict__ bc,
    const float* __restrict__ Wo, const float* __restrict__ Uo, const float* __restrict__ bo,
    float* __restrict__ out,
    u64* __restrict__ hrec)    // 2 parities x 8192 records x 8B = 128 KB
{
    __shared__ _Float16 xbuf[2 * BATCH * XSTRIDE];   // ~65 KB, double-buffered
    __shared__ float    gbuf[2 * BATCH * GSTRIDE];   // ~8.5 KB, double-buffered

    const int tid  = threadIdx.x;
    const int wg   = blockIdx.x;
    const int lane = tid & 63;
    const int wave = tid >> 6;
    const int mt   = wave & 1;
    const int nt   = wave >> 1;
    const int row  = mt * 16 + (lane & 15);
    const int kq   = lane >> 4;

    // ---- elementwise identity ---------------------------------------------
    const int eb   = tid >> 3;          // batch 0..31
    const int ej   = tid & 7;           // local h-col 0..7
    const int ecol = wg * HC + ej;

    // ---- publish h0 FIRST (epoch 1, parity 0) so stragglers can proceed ---
    float c_state = init_states[BATCH * H + eb * H + ecol];
    {
        _Float16 h0 = (_Float16)init_states[eb * H + ecol];
        u32 hu  = (u32)__builtin_bit_cast(unsigned short, h0);
        u32 oth = __shfl_down(hu, 1);
        if ((tid & 1) == 0) {
            // record addr: kk = wg>>2, kq = wg&3, s = ej>>1, row = eb
            const int ridx = (wg >> 2) * 512 + (ej >> 1) * 128 + eb * 4 + (wg & 3);
            AT_ST_U64(&hrec[ridx], ((u64)1u << 32) | (u64)(hu | (oth << 16)));
        }
    }

    // ---- one-time: weight B-fragments into VGPRs --------------------------
    const int n_local = lane & 15;
    const int gi   = nt * 2 + (n_local >> 3);
    const int wcol = wg * HC + (n_local & 7);
    const float* Wmat = (gi == 0) ? Wi : (gi == 1) ? Wf : (gi == 2) ? Wc : Wo;
    const float* Umat = (gi == 0) ? Ui : (gi == 1) ? Uf : (gi == 2) ? Uc : Uo;

    half8 bfrag[32];                    // 128 VGPRs/lane, persistent
    #pragma unroll
    for (int kk = 0; kk < 16; ++kk) {
        #pragma unroll
        for (int jj = 0; jj < 8; ++jj) {
            int k = kk * 32 + kq * 8 + jj;
            bfrag[kk][jj]      = (_Float16)Wmat[k * H + wcol];
            bfrag[16 + kk][jj] = (_Float16)Umat[k * H + wcol];
        }
    }

    const float bi_v = bi[ecol], bf_v = bf[ecol], bc_v = bc[ecol], bo_v = bo[ecol];

    // ---- staging / x-MFMA helpers -----------------------------------------
    auto stage = [&](int t, int buf) {
        const int sb = tid >> 3;
        const int so = (tid & 7) * 4;
        const float* xr = x + ((size_t)sb * T_STEPS + t) * DIN;
        _Float16* xb = &xbuf[buf * (BATCH * XSTRIDE)];
        #pragma unroll
        for (int q = 0; q < 16; ++q) {
            int colq = so + q * 32;
            float4 v = *(const float4*)(xr + colq);
            half4v hv = { (_Float16)v.x, (_Float16)v.y,
                          (_Float16)v.z, (_Float16)v.w };
            *(half4v*)&xb[sb * XSTRIDE + colq] = hv;
        }
    };
    auto xmm = [&](int buf) -> f32x4 {
        f32x4 ax  = {0.f, 0.f, 0.f, 0.f};
        f32x4 ax2 = {0.f, 0.f, 0.f, 0.f};
        const _Float16* xr2 = &xbuf[buf * (BATCH * XSTRIDE) + row * XSTRIDE + kq * 8];
        #pragma unroll
        for (int kk = 0; kk < 16; kk += 2) {
            half8 a0 = *(const half8*)(xr2 + kk * 32);
            half8 a1 = *(const half8*)(xr2 + (kk + 1) * 32);
            ax  = __builtin_amdgcn_mfma_f32_16x16x32_f16(a0, bfrag[kk],     ax,  0, 0, 0);
            ax2 = __builtin_amdgcn_mfma_f32_16x16x32_f16(a1, bfrag[kk + 1], ax2, 0, 0, 0);
        }
        #pragma unroll
        for (int r = 0; r < 4; ++r) ax[r] += ax2[r];
        return ax;
    };

    // ---- prologue: stage x0,x1; x-MFMA(0). No grid barrier needed. --------
    stage(0, 0);
    stage(1, 1);
    __syncthreads();
    f32x4 acc_x = xmm(0);

    // consumer record base index (u64 units, without kk/s/parity)
    const int ridx_base = row * 4 + kq;
    // producer record index (u64 units, without parity)
    const int widx = (wg >> 2) * 512 + (ej >> 1) * 128 + eb * 4 + (wg & 3);

    // ---- main recurrence --------------------------------------------------
    for (int t = 0; t < T_STEPS; ++t) {
        const u64* rb = hrec + (size_t)(t & 1) * RECS_PER_PARITY;
        const u32 target = (u32)(t + 1);

        // poll-load the 64 self-validating records (fully coalesced)
        u64 rec[64];
        unsigned spins = 0;
        for (;;) {
            #pragma unroll
            for (int kk = 0; kk < 16; ++kk) {
                #pragma unroll
                for (int s = 0; s < 4; ++s)
                    rec[kk * 4 + s] = AT_LD_U64(&rb[kk * 512 + s * 128 + ridx_base]);
            }
            int ok = 1;
            #pragma unroll
            for (int i = 0; i < 64; ++i)
                ok &= ((u32)(rec[i] >> 32) == target);
            if (__all(ok)) break;
            if (++spins > 300000u) break;   // safety valve
        }

        // h-half matmul from registers
        float* gb = &gbuf[(t & 1) * (BATCH * GSTRIDE)];
        {
            f32x4 acc  = acc_x;
            f32x4 acc2 = {0.f, 0.f, 0.f, 0.f};
            #pragma unroll
            for (int kk = 0; kk < 16; kk += 2) {
                union { u32 d[4]; half8 h; } a0, a1;
                #pragma unroll
                for (int s = 0; s < 4; ++s) {
                    a0.d[s] = (u32)rec[kk * 4 + s];
                    a1.d[s] = (u32)rec[(kk + 1) * 4 + s];
                }
                acc  = __builtin_amdgcn_mfma_f32_16x16x32_f16(a0.h, bfrag[16 + kk],     acc,  0, 0, 0);
                acc2 = __builtin_amdgcn_mfma_f32_16x16x32_f16(a1.h, bfrag[16 + kk + 1], acc2, 0, 0, 0);
            }
            #pragma unroll
            for (int r = 0; r < 4; ++r) {
                // C/D layout: col = lane&15, row = (lane>>4)*4 + r
                gb[(mt * 16 + kq * 4 + r) * GSTRIDE + nt * 16 + n_local] =
                    acc[r] + acc2[r];
            }
        }
        __syncthreads();   // the ONLY barrier per step

        // elementwise gates + state update + immediate h publish
        float h_val;
        {
            float pi = gb[eb * GSTRIDE + ej]      + bi_v;
            float pf = gb[eb * GSTRIDE + 8 + ej]  + bf_v;
            float pg = gb[eb * GSTRIDE + 16 + ej] + bc_v;
            float po = gb[eb * GSTRIDE + 24 + ej] + bo_v;
            float ig = sigmoidf_(pi);
            float fg = sigmoidf_(pf);
            float gg = tanhf_(pg);
            float og = sigmoidf_(po);
            c_state  = fg * c_state + ig * gg;
            h_val    = og * tanhf_(c_state);

            if (t + 1 < T_STEPS) {
                _Float16 hh = (_Float16)h_val;
                u32 hu  = (u32)__builtin_bit_cast(unsigned short, hh);
                u32 oth = __shfl_down(hu, 1);
                if ((tid & 1) == 0) {
                    AT_ST_U64(&hrec[(size_t)((t + 1) & 1) * RECS_PER_PARITY + widx],
                              ((u64)(u32)(t + 2) << 32) | (u64)(hu | (oth << 16)));
                }
            }
        }

        // ---- off-critical-path tail (overlaps other WGs' latency) ---------
        out[((size_t)eb * T_STEPS + t) * H + ecol] = h_val;
        if (t + 1 < T_STEPS) {
            acc_x = xmm((t + 1) & 1);                 // staged last iteration
            if (t + 2 < T_STEPS) stage(t + 2, t & 1); // buffer read 2 steps on
        }
    }
}

extern "C" void kernel_launch(void* const* d_in, const int* in_sizes, int n_in,
                              void* d_out, int out_size, void* d_ws, size_t ws_size,
                              hipStream_t stream) {
    const float* x           = (const float*)d_in[0];
    const float* init_states = (const float*)d_in[1];
    const float* Wi = (const float*)d_in[2];
    const float* Ui = (const float*)d_in[3];
    const float* bi = (const float*)d_in[4];
    const float* Wf = (const float*)d_in[5];
    const float* Uf = (const float*)d_in[6];
    const float* bf = (const float*)d_in[7];
    const float* Wc = (const float*)d_in[8];
    const float* Uc = (const float*)d_in[9];
    const float* bc = (const float*)d_in[10];
    const float* Wo = (const float*)d_in[11];
    const float* Uo = (const float*)d_in[12];
    const float* bo = (const float*)d_in[13];
    float* out = (float*)d_out;

    // ws: 2 x 8192 x 8B h-record buffers (128 KB). No memset needed: records
    // are validated by exact-match epochs (0xAAAAAAAA poison never matches),
    // and the harness re-poisons ws before every launch so no stale epochs
    // from a prior replay can match either.
    u64* hrec = (u64*)d_ws;

    lstm_persistent<<<dim3(NWG), dim3(256), 0, stream>>>(
        x, init_states, Wi, Ui, bi, Wf, Uf, bf, Wc, Uc, bc, Wo, Uo, bo,
        out, hrec);
}